// Round 12
// baseline (271.574 us; speedup 1.0000x reference)
//
#include <hip/hip_runtime.h>
#include <math.h>

namespace {

constexpr int D    = 49;
constexpr int H    = 8;
constexpr int L    = 4;
constexpr int HID  = 25;
constexpr int NCLS = 10;
constexpr int XS   = 68;    // LDS staging row stride (bf16 elems)
constexpr int WSM  = 4096;  // ushorts per padded 64x64 matrix in frag layout
constexpr int CST  = 2464;  // f32 composed-matrix stride (50 rows x 49 cols, padded)
// fold 1/(sqrt(49)+1e-6) * log2(e) into Wk so softmax uses exp2 directly
constexpr float SCLF  = 1.44269504088896f / (7.0f + 1e-6f);
constexpr float CLIP2 = 30.0f * 1.44269504088896f;  // clip bounds in log2 domain

typedef __attribute__((ext_vector_type(4))) short short4v;
typedef __attribute__((ext_vector_type(8))) short short8v;
typedef __attribute__((ext_vector_type(4))) float float4v;
typedef __attribute__((ext_vector_type(8))) __bf16 bf16x8;

__device__ __forceinline__ float4v mfma32(short8v a, short8v b, float4v c) {
  return __builtin_amdgcn_mfma_f32_16x16x32_bf16(a, b, c, 0, 0, 0);
}

__device__ __forceinline__ unsigned short f2bf(float x) {  // RNE
  unsigned u = __float_as_uint(x);
  return (unsigned short)((u + 0x7FFFu + ((u >> 16) & 1u)) >> 16);
}

__device__ __forceinline__ short8v cvt8(float4v lo, float4v hi) {
  bf16x8 b = {(__bf16)lo[0], (__bf16)lo[1], (__bf16)lo[2], (__bf16)lo[3],
              (__bf16)hi[0], (__bf16)hi[1], (__bf16)hi[2], (__bf16)hi[3]};
  return __builtin_bit_cast(short8v, b);
}

__device__ __forceinline__ float exp2_hw(float x) {  // x bounded by clip: safe
  float r;
  asm("v_exp_f32 %0, %1" : "=v"(r) : "v"(x));
  return r;
}

__device__ __forceinline__ float4v splat4(float x) {
  float4v v; v[0] = x; v[1] = x; v[2] = x; v[3] = x; return v;
}

__device__ __forceinline__ short8v wsld8(const unsigned short* __restrict__ w,
                                         int t, int nt, int lane) {
  return *reinterpret_cast<const short8v*>(w + ((t * 4 + nt) * 64 + lane) * 8);
}

// acc(cfrag of OUT^T) = W^T @ SRC   (all biases live inside W via ones-column)
__device__ __forceinline__ void mmT8(const unsigned short* __restrict__ w,
                                     const short8v (&src)[2][4],
                                     int lane, float4v (&acc)[4][4]) {
  #pragma unroll
  for (int mt = 0; mt < 4; ++mt)
    #pragma unroll
    for (int nt = 0; nt < 4; ++nt) acc[mt][nt] = splat4(0.0f);
  #pragma unroll
  for (int t = 0; t < 2; ++t) {
    short8v a[4];
    #pragma unroll
    for (int mt = 0; mt < 4; ++mt) a[mt] = wsld8(w, t, mt, lane);
    #pragma unroll
    for (int nt = 0; nt < 4; ++nt)
      #pragma unroll
      for (int mt = 0; mt < 4; ++mt)
        acc[mt][nt] = mfma32(a[mt], src[t][nt], acc[mt][nt]);
  }
}

// ---- prep A: per head, Wfull = Wv@Wh@Wout (rows 0-48), row 49 = bv@Wh@Wout;
//      ch = bh@Wout (accumulated into the layer's W12 bias row by prep B) ----
__global__ void __launch_bounds__(256)
prep_compose_head(const float* __restrict__ Wv, const float* __restrict__ Wh,
                  const float* __restrict__ Wout,
                  const float* __restrict__ bv, const float* __restrict__ bh,
                  float* __restrict__ wfullf, float* __restrict__ chf) {
  const int m = blockIdx.x;  // head-layer 0..31
  __shared__ float A[D * D], B[D * D], T[D * D];
  const int tid = threadIdx.x;
  const float* wh = Wh + (size_t)m * D * D;
  const float* wo = Wout + (size_t)m * D * D;
  const float* wv = Wv + (size_t)m * D * D;
  for (int i = tid; i < D * D; i += 256) { A[i] = wh[i]; B[i] = wo[i]; }
  __syncthreads();
  for (int i = tid; i < D * D; i += 256) {  // T = Wh @ Wout
    const int r = i / D, c = i - r * D;
    float s = 0.0f;
    #pragma unroll 1
    for (int k = 0; k < D; ++k) s = fmaf(A[r * D + k], B[k * D + c], s);
    T[i] = s;
  }
  __syncthreads();
  for (int i = tid; i < D * D; i += 256) A[i] = wv[i];  // A <- Wv
  __syncthreads();
  float* dst = wfullf + (size_t)m * CST;
  for (int i = tid; i < D * D; i += 256) {  // Wfull = Wv @ T
    const int r = i / D, c = i - r * D;
    float s = 0.0f;
    #pragma unroll 1
    for (int k = 0; k < D; ++k) s = fmaf(A[r * D + k], T[k * D + c], s);
    dst[i] = s;
  }
  if (tid < D) {
    float s = 0.0f, s2 = 0.0f;
    #pragma unroll 1
    for (int k = 0; k < D; ++k) {
      s  = fmaf(bv[m * D + k], T[k * D + tid], s);
      s2 = fmaf(bh[m * D + k], B[k * D + tid], s2);
    }
    dst[D * D + tid]  = s;   // row 49 (stored right after the 49x49 block)
    chf[m * 64 + tid] = s2;
  }
}

// ---- prep B: per layer, W12 = W1@W2 (rows 0-48),
//      row 49 = b1@W2 + b2 + (sum_h ch)@W12 ----
__global__ void __launch_bounds__(256)
prep_compose_layer(const float* __restrict__ W1, const float* __restrict__ W2,
                   const float* __restrict__ b1, const float* __restrict__ b2,
                   const float* __restrict__ chf, float* __restrict__ w12f) {
  const int l = blockIdx.x;  // 0..3
  __shared__ float A[D * D], B[D * D], M[D * D];
  __shared__ float Cv[D];
  const int tid = threadIdx.x;
  for (int i = tid; i < D * D; i += 256) {
    A[i] = W1[(size_t)l * D * D + i];
    B[i] = W2[(size_t)l * D * D + i];
  }
  if (tid < D) {
    float s = 0.0f;
    #pragma unroll
    for (int h = 0; h < H; ++h) s += chf[(l * H + h) * 64 + tid];
    Cv[tid] = s;
  }
  __syncthreads();
  float* dst = w12f + (size_t)l * CST;
  for (int i = tid; i < D * D; i += 256) {  // M = W1 @ W2
    const int r = i / D, c = i - r * D;
    float s = 0.0f;
    #pragma unroll 1
    for (int k = 0; k < D; ++k) s = fmaf(A[r * D + k], B[k * D + c], s);
    M[i] = s;
    dst[i] = s;
  }
  __syncthreads();
  if (tid < D) {
    float s = b2[l * D + tid];
    #pragma unroll 1
    for (int k = 0; k < D; ++k) {
      s = fmaf(b1[l * D + k], B[k * D + tid], s);
      s = fmaf(Cv[k], M[k * D + tid], s);
    }
    dst[D * D + tid] = s;  // row 49
  }
}

// ---- prep C: pack 100 matrices into padded 64x64 bf16 K=32-native frag layout.
// m 0-31: Wq (+bq row); 32-63: Wk*SCLF (+bk*SCLF row); 64-95: Wfull composed
// (diag49 = 1/8 for the den/ones trick); 96-99: W12 composed (diag49 = 1). ----
__global__ void __launch_bounds__(256)
prep_pack(const float* __restrict__ Wq, const float* __restrict__ Wk,
          const float* __restrict__ bq, const float* __restrict__ bk,
          const float* __restrict__ wfullf, const float* __restrict__ w12f,
          unsigned short* __restrict__ ws) {
  const int m = blockIdx.x;  // 0..99
  const int tid = threadIdx.x;
  const int lane = tid & 63;
  const int gg = (lane >> 4) & 3, cc = lane & 15;
  #pragma unroll
  for (int i = 0; i < 2; ++i) {
    const int p = ((tid >> 6) << 1) | i;  // 0..7
    const int tt = p >> 2, nt = p & 3;
    short8v v;
    #pragma unroll
    for (int j = 0; j < 8; ++j) {
      const int k = 32 * tt + ((j < 4) ? (4 * gg + j) : (16 + 4 * gg + j - 4));
      const int n = 16 * nt + cc;
      float f = 0.0f;
      if (m < 32) {
        if (k < D && n < D)       f = Wq[(size_t)m * D * D + k * D + n];
        else if (k == D && n < D) f = bq[m * D + n];
      } else if (m < 64) {
        const int hh = m - 32;
        if (k < D && n < D)       f = Wk[(size_t)hh * D * D + k * D + n] * SCLF;
        else if (k == D && n < D) f = bk[hh * D + n] * SCLF;
      } else if (m < 96) {
        const float* src = wfullf + (size_t)(m - 64) * CST;
        if (n < D && k <= D)       f = src[k * D + n];
        else if (k == D && n == D) f = 0.125f;
      } else {
        const float* src = w12f + (size_t)(m - 96) * CST;
        if (n < D && k <= D)       f = src[k * D + n];
        else if (k == D && n == D) f = 1.0f;
      }
      v[j] = (short)f2bf(f);
    }
    *reinterpret_cast<short8v*>(ws + (size_t)m * WSM + ((tt * 4 + nt) * 64 + lane) * 8) = v;
  }
}

__global__ void __launch_bounds__(64, 2)
encoder_kernel(const float* __restrict__ emb, const int* __restrict__ labels,
               const unsigned short* __restrict__ ws,
               const float* __restrict__ Wc1, const float* __restrict__ bc1,
               const float* __restrict__ Wc2, const float* __restrict__ bc2,
               float* __restrict__ ws_loss, float* __restrict__ ws_corr) {
  __shared__ unsigned short X[64 * XS];  // embedding staging only
  __shared__ float CLS[128];

  const int b = blockIdx.x;
  const int lane = threadIdx.x;          // one wave per block
  const int g = lane >> 4, c = lane & 15;

  // ---- stage embedding (64x64 bf16; col 49 = ones-column, rest pad 0) ----
  for (int idx = lane; idx < 64 * 64; idx += 64) {
    const int r = idx >> 6, cc = idx & 63;
    float v = 0.0f;
    if (cc == D) v = 1.0f;
    else if (r < D && cc < D) v = emb[(size_t)b * (D * D) + r * D + cc];
    X[r * XS + cc] = f2bf(v);
  }
  __syncthreads();

  short8v xf8[2][4];  // operand frag of X (contraction over d)
  #pragma unroll
  for (int t = 0; t < 2; ++t)
    #pragma unroll
    for (int nt = 0; nt < 4; ++nt) {
      const int base = (16 * nt + c) * XS + 32 * t + 4 * g;
      short4v lo = *reinterpret_cast<const short4v*>(&X[base]);
      short4v hi = *reinterpret_cast<const short4v*>(&X[base + 16]);
      xf8[t][nt] = __builtin_shufflevector(lo, hi, 0, 1, 2, 3, 4, 5, 6, 7);
    }

  float4v xacc[4][4];  // cfrag(x^T)

  #pragma unroll 1
  for (int l = 0; l < L; ++l) {
    float4v od[4][4];  // cfrag(od^T) f32 accumulator across heads
    #pragma unroll
    for (int mt = 0; mt < 4; ++mt)
      #pragma unroll
      for (int nt = 0; nt < 4; ++nt) od[mt][nt] = splat4(0.0f);

    // unroll 2: consecutive heads are independent until the od accumulate.
    #pragma unroll 2
    for (int h = 0; h < H; ++h) {
      const int lh = l * H + h;
      const unsigned short* wq = ws + (size_t)(0  + lh) * WSM;
      const unsigned short* wk = ws + (size_t)(32 + lh) * WSM;
      const unsigned short* wf = ws + (size_t)(64 + lh) * WSM;

      // ---- K^T (pre-scaled, log2 domain) and Q^T ----
      short8v kf8[2][4], qf8[2][4];
      {
        float4v ka[4][4];
        mmT8(wk, xf8, lane, ka);
        #pragma unroll
        for (int t = 0; t < 2; ++t)
          #pragma unroll
          for (int nt = 0; nt < 4; ++nt)
            kf8[t][nt] = cvt8(ka[2 * t][nt], ka[2 * t + 1][nt]);
      }
      {
        float4v qa[4][4];
        mmT8(wq, xf8, lane, qa);
        #pragma unroll
        for (int t = 0; t < 2; ++t)
          #pragma unroll
          for (int nt = 0; nt < 4; ++nt)
            qf8[t][nt] = cvt8(qa[2 * t][nt], qa[2 * t + 1][nt]);
      }

      // ---- S^T = K @ Q^T (log2 domain) ----
      float4v s[4][4];
      #pragma unroll
      for (int mt = 0; mt < 4; ++mt)
        #pragma unroll
        for (int nt = 0; nt < 4; ++nt) s[mt][nt] = splat4(0.0f);
      #pragma unroll
      for (int t = 0; t < 2; ++t)
        #pragma unroll
        for (int nt = 0; nt < 4; ++nt)
          #pragma unroll
          for (int mt = 0; mt < 4; ++mt)
            s[mt][nt] = mfma32(kf8[t][mt], qf8[t][nt], s[mt][nt]);

      // ---- U = X @ Wfull' (rows = patch, cols = o; col 49 = 1/8) ----
      short8v uf8[2][4];
      {
        float4v ua[4][4];
        #pragma unroll
        for (int nt = 0; nt < 4; ++nt)
          #pragma unroll
          for (int mt = 0; mt < 4; ++mt) ua[mt][nt] = splat4(0.0f);
        #pragma unroll
        for (int t = 0; t < 2; ++t) {
          short8v wff[4];
          #pragma unroll
          for (int nt = 0; nt < 4; ++nt) wff[nt] = wsld8(wf, t, nt, lane);
          #pragma unroll
          for (int nt = 0; nt < 4; ++nt)
            #pragma unroll
            for (int mt = 0; mt < 4; ++mt)
              ua[mt][nt] = mfma32(xf8[t][mt], wff[nt], ua[mt][nt]);
        }
        #pragma unroll
        for (int t = 0; t < 2; ++t)
          #pragma unroll
          for (int nt = 0; nt < 4; ++nt)
            uf8[t][nt] = cvt8(ua[2 * t][nt], ua[2 * t + 1][nt]);
      }

      // ---- max-free softmax: clip bounds exp2; pad keys masked at compile
      //      time (key j = 16mt+4g+r: mt==3,r>0 always pad; r==0 needs g==0) ----
      short8v pf8[2][4];
      #pragma unroll
      for (int mt = 0; mt < 4; ++mt)
        #pragma unroll
        for (int nt = 0; nt < 4; ++nt)
          #pragma unroll
          for (int r = 0; r < 4; ++r) {
            if (mt == 3 && r > 0) { s[mt][nt][r] = 0.0f; continue; }
            const float sv = fminf(fmaxf(s[mt][nt][r], -CLIP2), CLIP2);
            float p = exp2_hw(sv);
            if (mt == 3) p = (g == 0) ? p : 0.0f;
            s[mt][nt][r] = p;
          }
      #pragma unroll
      for (int t = 0; t < 2; ++t)
        #pragma unroll
        for (int nt = 0; nt < 4; ++nt)
          pf8[t][nt] = cvt8(s[2 * t][nt], s[2 * t + 1][nt]);

      // ---- ca = U^T-contract P~: od-contribution (unnormalized);
      //      row 49 = den/8 (U ones-col = 1/8); od += ca * (0.125/ca49) ----
      float4v ca[4][4];
      #pragma unroll
      for (int mt = 0; mt < 4; ++mt)
        #pragma unroll
        for (int nt = 0; nt < 4; ++nt) ca[mt][nt] = splat4(0.0f);
      #pragma unroll
      for (int t = 0; t < 2; ++t)
        #pragma unroll
        for (int nt = 0; nt < 4; ++nt)
          #pragma unroll
          for (int mt = 0; mt < 4; ++mt)
            ca[mt][nt] = mfma32(uf8[t][mt], pf8[t][nt], ca[mt][nt]);
      #pragma unroll
      for (int nt = 0; nt < 4; ++nt) {
        // row 49 = (mt=3, g=0, reg r=1); lane c holds col q=16nt+c at g=0
        const float inv = 0.125f / __shfl(ca[3][nt][1], c);
        const float4v iv = splat4(inv);
        #pragma unroll
        for (int mt = 0; mt < 4; ++mt)
          od[mt][nt] += ca[mt][nt] * iv;
      }
    }  // heads

    // ---- fused MLP: x^T = W12'^T @ od^T (bias+head-bias in row 49) ----
    short8v of8[2][4];
    #pragma unroll
    for (int t = 0; t < 2; ++t)
      #pragma unroll
      for (int nt = 0; nt < 4; ++nt)
        of8[t][nt] = cvt8(od[2 * t][nt], od[2 * t + 1][nt]);
    mmT8(ws + (size_t)(96 + l) * WSM, of8, lane, xacc);

    if (l < L - 1) {
      #pragma unroll
      for (int t = 0; t < 2; ++t)
        #pragma unroll
        for (int nt = 0; nt < 4; ++nt)
          xf8[t][nt] = cvt8(xacc[2 * t][nt], xacc[2 * t + 1][nt]);
    }
  }  // layers

  // ---- pooled[d] = mean over patch cols < 49 of x^T ----
  #pragma unroll
  for (int mt = 0; mt < 4; ++mt) {
    #pragma unroll
    for (int r = 0; r < 4; ++r) {
      float sv = xacc[mt][0][r] + xacc[mt][1][r] + xacc[mt][2][r];
      if (c == 0) sv += xacc[mt][3][r];  // patch 48; 49..63 pad
      sv += __shfl_xor(sv, 1);
      sv += __shfl_xor(sv, 2);
      sv += __shfl_xor(sv, 4);
      sv += __shfl_xor(sv, 8);
      if (c == 0) CLS[16 * mt + 4 * g + r] = sv * (1.0f / 49.0f);
    }
  }
  __syncthreads();

  // ---- classifier head (f32 scalar path) ----
  if (lane < HID) {
    float acc = bc1[lane];
    #pragma unroll 1
    for (int d = 0; d < D; ++d) acc = fmaf(CLS[d], Wc1[d * HID + lane], acc);
    CLS[64 + lane] = acc;
  }
  __syncthreads();
  if (lane < NCLS) {
    float acc = bc2[lane];
    #pragma unroll 1
    for (int j = 0; j < HID; ++j) acc = fmaf(CLS[64 + j], Wc2[j * NCLS + lane], acc);
    CLS[96 + lane] = acc;
  }
  __syncthreads();
  if (lane == 0) {
    float mx = CLS[96];
    int am = 0;
    #pragma unroll 1
    for (int cc = 1; cc < NCLS; ++cc) {
      const float v = CLS[96 + cc];
      if (v > mx) { mx = v; am = cc; }  // strict '>' == first max (jnp.argmax)
    }
    float se = 0.0f;
    #pragma unroll 1
    for (int cc = 0; cc < NCLS; ++cc) se += expf(CLS[96 + cc] - mx);
    const float lse = mx + logf(se);
    const int lbl = labels[b];
    ws_loss[b] = lse - CLS[96 + lbl];
    ws_corr[b] = (am == lbl) ? 1.0f : 0.0f;
  }
}

__global__ void __launch_bounds__(256)
reduce_kernel(const float* __restrict__ wsl, const float* __restrict__ wsc,
              float* __restrict__ out, int n) {
  __shared__ float sl[256];
  __shared__ float sc[256];
  const int t = threadIdx.x;
  float a = 0.0f, cc = 0.0f;
  for (int idx = t; idx < n; idx += 256) { a += wsl[idx]; cc += wsc[idx]; }
  sl[t] = a; sc[t] = cc;
  __syncthreads();
  for (int s = 128; s > 0; s >>= 1) {
    if (t < s) { sl[t] += sl[t + s]; sc[t] += sc[t + s]; }
    __syncthreads();
  }
  if (t == 0) {
    out[0] = sl[0] / (float)n;
    out[1] = sc[0] / (float)n;
  }
}

}  // namespace

extern "C" void kernel_launch(void* const* d_in, const int* in_sizes, int n_in,
                              void* d_out, int out_size, void* d_ws, size_t ws_size,
                              hipStream_t stream) {
  const float* emb    = (const float*)d_in[0];
  const int*   labels = (const int*)d_in[1];
  const float* Wq   = (const float*)d_in[2];
  const float* bq   = (const float*)d_in[3];
  const float* Wk   = (const float*)d_in[4];
  const float* bk   = (const float*)d_in[5];
  const float* Wv   = (const float*)d_in[6];
  const float* bv   = (const float*)d_in[7];
  const float* Wh   = (const float*)d_in[8];
  const float* bh   = (const float*)d_in[9];
  const float* Wout = (const float*)d_in[10];
  const float* W1   = (const float*)d_in[11];
  const float* b1   = (const float*)d_in[12];
  const float* W2   = (const float*)d_in[13];
  const float* b2   = (const float*)d_in[14];
  const float* Wc1  = (const float*)d_in[15];
  const float* bc1  = (const float*)d_in[16];
  const float* Wc2  = (const float*)d_in[17];
  const float* bc2  = (const float*)d_in[18];

  const int B = in_sizes[1];  // 2048
  // layout: [frag bf16 100*WSM][wfullf 32*CST f32][w12f 4*CST f32]
  //         [chf 32*64 f32][loss B][corr B]
  const size_t fragB  = (size_t)100 * WSM * sizeof(unsigned short);
  const size_t wfullB = (size_t)32 * CST * sizeof(float);
  const size_t w12B   = (size_t)4 * CST * sizeof(float);
  const size_t chB    = (size_t)32 * 64 * sizeof(float);
  const size_t need = fragB + wfullB + w12B + chB + (size_t)2 * B * sizeof(float);
  if (ws_size < need) return;

  unsigned short* wsb = (unsigned short*)d_ws;
  float* wfullf = (float*)((char*)d_ws + fragB);
  float* w12f   = (float*)((char*)d_ws + fragB + wfullB);
  float* chf    = (float*)((char*)d_ws + fragB + wfullB + w12B);
  float* wsf    = (float*)((char*)d_ws + fragB + wfullB + w12B + chB);
  float* out = (float*)d_out;

  prep_compose_head<<<32, 256, 0, stream>>>(Wv, Wh, Wout, bv, bh, wfullf, chf);
  prep_compose_layer<<<4, 256, 0, stream>>>(W1, W2, b1, b2, chf, w12f);
  prep_pack<<<100, 256, 0, stream>>>(Wq, Wk, bq, bk, wfullf, w12f, wsb);
  encoder_kernel<<<B, 64, 0, stream>>>(emb, labels, wsb, Wc1, bc1, Wc2, bc2,
                                       wsf, wsf + B);
  reduce_kernel<<<1, 256, 0, stream>>>(wsf, wsf + B, out, B);
}